// Round 22
// baseline (535.347 us; speedup 1.0000x reference)
//
#include <hip/hip_runtime.h>
#include <hip/hip_fp16.h>
#include <cstdint>
#include <cstddef>

#define DT_F 0.5f
#define ELL_C 64        // fixed ELL row capacity (Poisson(16): max deg ~45)
#define NSUB 512        // dst sub-bins (each ~n/512 nodes)
#define LCAP 14         // LDS bin depth in k_bin512
#define NBIN 1024       // k_bin512 blocks
#define NLOC_MAX 208    // max nodes per sub-bin for LDS row assembly

typedef _Float16 f16x8 __attribute__((ext_vector_type(8)));
typedef float f32x4 __attribute__((ext_vector_type(4)));
typedef unsigned int u32x4 __attribute__((ext_vector_type(4)));  // NT-loadable

__device__ __forceinline__ __half2 u32_as_h2(uint32_t u) {
    union { uint32_t u; __half2 h; } c; c.u = u; return c.h;
}

// ---------------------------------------------------------------------------
// edge_index dtype detection (reference says int64; harness doc says int).
__global__ void detect_i64(const long long* __restrict__ ei, int E, int n,
                           int* __restrict__ flag) {
    __shared__ int ok;
    if (threadIdx.x == 0) ok = 1;
    __syncthreads();
    int m = E < 2048 ? E : 2048;
    for (int i = threadIdx.x; i < m; i += blockDim.x) {
        long long v = ei[i];
        if (v < 0 || v >= (long long)n) ok = 0;  // benign race, all write 0
    }
    __syncthreads();
    if (threadIdx.x == 0) flag[0] = ok;
}

__device__ __forceinline__ int ld_idx(const void* ei, size_t pos, int w64) {
    return w64 ? (int)((const long long*)ei)[pos] : ((const int*)ei)[pos];
}

// ---------------------------------------------------------------------------
// Build pass 1 (validated R17): 512-way LDS binning, flush to staging.
__global__ void k_bin512(const void* __restrict__ ei, const float* __restrict__ ew,
                         const int* __restrict__ flag, int E, int n,
                         int colbits, float scale,
                         int2* __restrict__ staging, int scap2,
                         int* __restrict__ gcur,
                         int2* __restrict__ ovf, int* __restrict__ ovcnt, int ovcap) {
    __shared__ int2 bins[NSUB][LCAP];   // 57344 B
    __shared__ int bcnt[NSUB];
    __shared__ int gbase[NSUB];
    int tid = threadIdx.x;
    for (int b = tid; b < NSUB; b += 256) bcnt[b] = 0;
    __syncthreads();
    int per = (E + NBIN - 1) / NBIN;
    int e0 = blockIdx.x * per;
    int e1 = e0 + per; if (e1 > E) e1 = E;
    int w64 = flag[0];
    for (int e = e0 + tid; e < e1; e += 256) {
        int d = ld_idx(ei, (size_t)E + e, w64);
        uint32_t w15 = (uint32_t)(ew[e] * scale + 0.5f);
        uint32_t sw = (w15 << colbits) | (uint32_t)ld_idx(ei, e, w64);
        int sb = (int)(((long long)d * NSUB) / n);
        int p = atomicAdd(&bcnt[sb], 1);
        if (p < LCAP) {
            bins[sb][p] = make_int2(d, (int)sw);
        } else {
            int q = atomicAdd(ovcnt, 1);
            if (q < ovcap) ovf[q] = make_int2(d, (int)sw);
        }
    }
    __syncthreads();
    for (int b = tid; b < NSUB; b += 256) {
        int c = bcnt[b]; if (c > LCAP) c = LCAP;
        bcnt[b] = c;
        gbase[b] = atomicAdd(&gcur[b], c);
    }
    __syncthreads();
    for (int b = tid; b < NSUB; b += 256) {
        int c = bcnt[b], gb = gbase[b];
        for (int i = 0; i < c; ++i) {
            int pos = gb + i;
            if (pos < scap2) {
                staging[(size_t)b * scap2 + pos] = bins[b][i];
            } else {
                int q = atomicAdd(ovcnt, 1);
                if (q < ovcap) ovf[q] = bins[b][i];
            }
        }
    }
}

// Build pass 2 (validated R17): one block per sub-bin, LDS row assembly,
// coalesced single-write flush.
__global__ void k_scatter512(const int2* __restrict__ staging, int scap2,
                             const int* __restrict__ gcur, int n,
                             int* __restrict__ cnt, uint32_t* __restrict__ ev) {
    __shared__ uint32_t lrow[NLOC_MAX * 64];   // 53248 B
    __shared__ int lcnt[NLOC_MAX];
    int sb = blockIdx.x;
    int lo = (int)(((long long)sb * n + NSUB - 1) / NSUB);
    int hi = (int)(((long long)(sb + 1) * n + NSUB - 1) / NSUB);
    if (hi > n) hi = n;
    int nloc = hi - lo;
    int tid = threadIdx.x;
    int tot = gcur[sb]; if (tot > scap2) tot = scap2;
    if (nloc <= NLOC_MAX) {
        for (int i = tid; i < nloc; i += 256) lcnt[i] = 0;
        __syncthreads();
        for (int i = tid; i < tot; i += 256) {
            int2 t = staging[(size_t)sb * scap2 + i];
            int ni = t.x - lo;
            int p = atomicAdd(&lcnt[ni], 1);
            if (p < ELL_C) lrow[ni * 64 + p] = (uint32_t)t.y;
        }
        __syncthreads();
        for (int idx = tid; idx < nloc * 64; idx += 256) {
            int ni = idx >> 6, e = idx & 63;
            int c = lcnt[ni]; if (c > ELL_C) c = ELL_C;
            if (e < c) ev[(size_t)(lo + ni) * 64 + e] = lrow[idx];
        }
        for (int i = tid; i < nloc; i += 256) {
            int c = lcnt[i]; if (c > ELL_C) c = ELL_C;
            cnt[lo + i] = c;
        }
    } else {  // generic-n fallback: direct scatter (cnt pre-zeroed)
        for (int i = tid; i < tot; i += 256) {
            int2 t = staging[(size_t)sb * scap2 + i];
            int p = atomicAdd(&cnt[t.x], 1);
            if (p < ELL_C) ev[(size_t)t.x * 64 + p] = (uint32_t)t.y;
        }
    }
}

// Append rare overflow edges (normally 0) after row assembly.
__global__ void k_overflow(const int2* __restrict__ ovf, const int* __restrict__ ovcnt,
                           int ovcap, int* __restrict__ cnt, uint32_t* __restrict__ ev) {
    int tot = ovcnt[0]; if (tot > ovcap) tot = ovcap;
    for (int i = blockIdx.x * blockDim.x + threadIdx.x; i < tot;
         i += gridDim.x * blockDim.x) {
        int2 t = ovf[i];
        int p = atomicAdd(&cnt[t.x], 1);
        if (p < ELL_C) ev[(size_t)t.x * 64 + p] = (uint32_t)t.y;
    }
}

// ---------------------------------------------------------------------------
// I0 -> fp16 gather mirror.
__global__ void k_h16(const float* __restrict__ x, __half* __restrict__ y, int n) {
    int i = blockIdx.x * blockDim.x + threadIdx.x;
    if (i < n) y[i] = __float2half(x[i]);
}

// ---------------------------------------------------------------------------
// Projection via MATRIX CORES (validated R19: proj 72 -> <~15us, absmax ok).
__global__ void proj_mfma(const float* __restrict__ nf,
                          const float* __restrict__ Wm,   // (65,64) row-major
                          const float* __restrict__ Wsf,  // (65,64)
                          const float* __restrict__ bh,
                          __half* __restrict__ PMh, float* __restrict__ HC,
                          int n) {
    __shared__ _Float16 sW[2][8][512];   // [matrix][frag ks*4+jt][lane*8+el]
    int tid = threadIdx.x;
    for (int idx = tid; idx < 8192; idx += 256) {
        int m   = idx >> 12;
        int rem = idx & 4095;
        int f   = rem >> 9;
        int ln  = (rem >> 3) & 63;
        int el  = rem & 7;
        int ks = f >> 2, jt = f & 3;
        int k = ks * 32 + (ln >> 4) * 8 + el;
        int j = jt * 16 + (ln & 15);
        const float* W = m ? Wsf : Wm;
        sW[m][f][ln * 8 + el] = (_Float16)W[k * 64 + j];
    }
    __syncthreads();
    int w = tid >> 6, l = tid & 63;
    int kg = l >> 4;
    int node0 = blockIdx.x * 64 + w * 16;
    int nodeA = node0 + (l & 15);                  // A-fragment row
    f16x8 a0 = {}, a1 = {};
    if (nodeA < n) {
        const float* p = nf + (size_t)nodeA * 64 + kg * 8;
        float4 u0 = *(const float4*)(p);
        float4 u1 = *(const float4*)(p + 4);
        float4 v0 = *(const float4*)(p + 32);
        float4 v1 = *(const float4*)(p + 36);
        a0[0]=(_Float16)u0.x; a0[1]=(_Float16)u0.y; a0[2]=(_Float16)u0.z; a0[3]=(_Float16)u0.w;
        a0[4]=(_Float16)u1.x; a0[5]=(_Float16)u1.y; a0[6]=(_Float16)u1.z; a0[7]=(_Float16)u1.w;
        a1[0]=(_Float16)v0.x; a1[1]=(_Float16)v0.y; a1[2]=(_Float16)v0.z; a1[3]=(_Float16)v0.w;
        a1[4]=(_Float16)v1.x; a1[5]=(_Float16)v1.y; a1[6]=(_Float16)v1.z; a1[7]=(_Float16)v1.w;
    }
    f32x4 accm[4], accs[4];
#pragma unroll
    for (int jt = 0; jt < 4; ++jt) { accm[jt] = (f32x4){0.f,0.f,0.f,0.f};
                                     accs[jt] = (f32x4){0.f,0.f,0.f,0.f}; }
#pragma unroll
    for (int jt = 0; jt < 4; ++jt) {
        f16x8 bm0 = *(const f16x8*)&sW[0][jt][l * 8];
        f16x8 bm1 = *(const f16x8*)&sW[0][4 + jt][l * 8];
        accm[jt] = __builtin_amdgcn_mfma_f32_16x16x32_f16(a0, bm0, accm[jt], 0, 0, 0);
        accm[jt] = __builtin_amdgcn_mfma_f32_16x16x32_f16(a1, bm1, accm[jt], 0, 0, 0);
        f16x8 bs0 = *(const f16x8*)&sW[1][jt][l * 8];
        f16x8 bs1 = *(const f16x8*)&sW[1][4 + jt][l * 8];
        accs[jt] = __builtin_amdgcn_mfma_f32_16x16x32_f16(a0, bs0, accs[jt], 0, 0, 0);
        accs[jt] = __builtin_amdgcn_mfma_f32_16x16x32_f16(a1, bs1, accs[jt], 0, 0, 0);
    }
#pragma unroll
    for (int r = 0; r < 4; ++r) {
        int node = node0 + kg * 4 + r;              // D row
        if (node < n) {
#pragma unroll
            for (int jt = 0; jt < 4; ++jt) {
                int j = jt * 16 + (l & 15);         // D col
                PMh[(size_t)node * 64 + j] = __float2half(accm[jt][r]);
                HC[(size_t)node * 64 + j] = accs[jt][r] + bh[j];
            }
        }
    }
}

// Hoisted constant aggregation on ELL rows, fp16 PM gather, 8-edge unroll.
// ev/HCin are read-once streams -> NON-TEMPORAL (keep L2 for PMh 16x reuse).
__global__ void edge_wide_ell(const int* __restrict__ cnt,
                              const uint32_t* __restrict__ ev,
                              const __half* __restrict__ PMh,
                              const float* __restrict__ HCin,
                              __half* __restrict__ HCh, int n,
                              int colbits, float inv_scale) {
    int wave = (blockIdx.x * blockDim.x + threadIdx.x) >> 6;
    int lane = threadIdx.x & 63;
    if (wave >= n) return;
    uint32_t cmask = (1u << colbits) - 1;
    int deg = cnt[wave]; if (deg > ELL_C) deg = ELL_C;
    int d8 = deg & ~7;
    int d4 = deg & ~3;
    const u32x4* row4 = (const u32x4*)(ev + (size_t)wave * ELL_C);
    const uint32_t* row = ev + (size_t)wave * ELL_C;
    float acc0 = 0.f, acc1 = 0.f, acc2 = 0.f, acc3 = 0.f;
    for (int e = 0; e < d8; e += 8) {
        u32x4 qa = __builtin_nontemporal_load(&row4[e >> 2]);
        u32x4 qb = __builtin_nontemporal_load(&row4[(e >> 2) + 1]);
        float v0 = __half2float(PMh[(size_t)(qa[0] & cmask) * 64 + lane]);
        float v1 = __half2float(PMh[(size_t)(qa[1] & cmask) * 64 + lane]);
        float v2 = __half2float(PMh[(size_t)(qa[2] & cmask) * 64 + lane]);
        float v3 = __half2float(PMh[(size_t)(qa[3] & cmask) * 64 + lane]);
        float v4 = __half2float(PMh[(size_t)(qb[0] & cmask) * 64 + lane]);
        float v5 = __half2float(PMh[(size_t)(qb[1] & cmask) * 64 + lane]);
        float v6 = __half2float(PMh[(size_t)(qb[2] & cmask) * 64 + lane]);
        float v7 = __half2float(PMh[(size_t)(qb[3] & cmask) * 64 + lane]);
        acc0 = fmaf((float)(qa[0] >> colbits) * inv_scale, v0, acc0);
        acc1 = fmaf((float)(qa[1] >> colbits) * inv_scale, v1, acc1);
        acc2 = fmaf((float)(qa[2] >> colbits) * inv_scale, v2, acc2);
        acc3 = fmaf((float)(qa[3] >> colbits) * inv_scale, v3, acc3);
        acc0 = fmaf((float)(qb[0] >> colbits) * inv_scale, v4, acc0);
        acc1 = fmaf((float)(qb[1] >> colbits) * inv_scale, v5, acc1);
        acc2 = fmaf((float)(qb[2] >> colbits) * inv_scale, v6, acc2);
        acc3 = fmaf((float)(qb[3] >> colbits) * inv_scale, v7, acc3);
    }
    if (d8 < d4) {
        u32x4 q = __builtin_nontemporal_load(&row4[d8 >> 2]);
        float v0 = __half2float(PMh[(size_t)(q[0] & cmask) * 64 + lane]);
        float v1 = __half2float(PMh[(size_t)(q[1] & cmask) * 64 + lane]);
        float v2 = __half2float(PMh[(size_t)(q[2] & cmask) * 64 + lane]);
        float v3 = __half2float(PMh[(size_t)(q[3] & cmask) * 64 + lane]);
        acc0 = fmaf((float)(q[0] >> colbits) * inv_scale, v0, acc0);
        acc1 = fmaf((float)(q[1] >> colbits) * inv_scale, v1, acc1);
        acc2 = fmaf((float)(q[2] >> colbits) * inv_scale, v2, acc2);
        acc3 = fmaf((float)(q[3] >> colbits) * inv_scale, v3, acc3);
    }
    for (int e = d4; e < deg; ++e) {                 // scalar tail (<=3)
        uint32_t q = row[e];
        acc0 = fmaf((float)(q >> colbits) * inv_scale,
                    __half2float(PMh[(size_t)(q & cmask) * 64 + lane]), acc0);
    }
    size_t o = (size_t)wave * 64 + lane;
    float hc = __builtin_nontemporal_load(&HCin[o]);
    __half r = __float2half(hc + ((acc0 + acc1) + (acc2 + acc3)));
    HCh[o] = r;
}

// ---------------------------------------------------------------------------
// Fused per-step kernel, 4 nodes/wave, 16 lanes/node, ELL rows.
// Streaming reads (HCh, ev) NON-TEMPORAL so L2 stays resident for the hot
// 200KB Ih gather mirror (the latency-critical access). (Validated R12-R19.)
__global__ void step_fused4(const int* __restrict__ cnt,
                            const uint32_t* __restrict__ ev,
                            const uint32_t* __restrict__ HChu,  // __half2 as u32
                            const float4* __restrict__ wmL4,  // W_msg row 64
                            const float4* __restrict__ wsL4,  // W_self row 64
                            const float4* __restrict__ wb4, const float* __restrict__ bb,
                            const float4* __restrict__ wg4, const float* __restrict__ bg,
                            const float* __restrict__ I_old,   // fp32 (out row)
                            const __half* __restrict__ Ih_old, // fp16 mirror
                            __half* __restrict__ Ih_new,
                            float* __restrict__ S,
                            float* __restrict__ Iseq_t,      // = I_new (fp32)
                            float* __restrict__ beta_out, float* __restrict__ gamma_out,
                            int n, int last, int colbits, float inv_scale) {
    int wid  = (blockIdx.x * blockDim.x + threadIdx.x) >> 6;
    int lane = threadIdx.x & 63;
    int l16  = lane & 15;
    int node = wid * 4 + (lane >> 4);
    if (node >= n) return;
    uint32_t cmask = (1u << colbits) - 1;
    int deg = cnt[node]; if (deg > ELL_C) deg = ELL_C;
    const uint32_t* row = ev + (size_t)node * ELL_C;
    float f = 0.f;
    for (int e = l16; e < deg; e += 16) {
        uint32_t p = __builtin_nontemporal_load(&row[e]);
        f = fmaf((float)(p >> colbits) * inv_scale,
                 __half2float(Ih_old[p & cmask]), f);
    }
    f += __shfl_xor(f, 1); f += __shfl_xor(f, 2);
    f += __shfl_xor(f, 4); f += __shfl_xor(f, 8);   // force, all 16 lanes
    float Iv = I_old[node];
    uint32_t uA = __builtin_nontemporal_load(&HChu[(size_t)node * 32 + l16 * 2]);
    uint32_t uB = __builtin_nontemporal_load(&HChu[(size_t)node * 32 + l16 * 2 + 1]);
    float2 fA = __half22float2(u32_as_h2(uA));
    float2 fB = __half22float2(u32_as_h2(uB));
    float4 wm = wmL4[l16], wsv = wsL4[l16];
    float4 h;
    h.x = fmaxf(fmaf(f, wm.x, fmaf(Iv, wsv.x, fA.x)), 0.f);
    h.y = fmaxf(fmaf(f, wm.y, fmaf(Iv, wsv.y, fA.y)), 0.f);
    h.z = fmaxf(fmaf(f, wm.z, fmaf(Iv, wsv.z, fB.x)), 0.f);
    h.w = fmaxf(fmaf(f, wm.w, fmaf(Iv, wsv.w, fB.y)), 0.f);
    float4 wbv = wb4[l16], wgv = wg4[l16];
    float pb = fmaf(h.x, wbv.x, fmaf(h.y, wbv.y, fmaf(h.z, wbv.z, h.w * wbv.w)));
    float pg = fmaf(h.x, wgv.x, fmaf(h.y, wgv.y, fmaf(h.z, wgv.z, h.w * wgv.w)));
    pb += __shfl_xor(pb, 1); pg += __shfl_xor(pg, 1);
    pb += __shfl_xor(pb, 2); pg += __shfl_xor(pg, 2);
    pb += __shfl_xor(pb, 4); pg += __shfl_xor(pg, 4);
    pb += __shfl_xor(pb, 8); pg += __shfl_xor(pg, 8);
    if (l16 == 0) {
        float beta  = 1.f / (1.f + expf(-(pb + bb[0])));
        float gamma = 1.f / (1.f + expf(-(pg + bg[0])));
        float fc = fminf(fmaxf(f, 0.f), 1000.f);
        float Sv = S[node];
        float inf_ = beta * Sv * fc;
        float rec  = gamma * Iv;
        float Sn = fminf(fmaxf(Sv - inf_ * DT_F, 0.f), 1.f);
        float In = fminf(fmaxf(Iv + (inf_ - rec) * DT_F, 0.f), 1.f);
        S[node] = Sn;
        __builtin_nontemporal_store(In, &Iseq_t[node]);
        Ih_new[node] = __float2half(In);   // gather mirror for step t+1
        if (last) { beta_out[node] = beta; gamma_out[node] = gamma; }
    }
}

// ---------------------------------------------------------------------------
extern "C" void kernel_launch(void* const* d_in, const int* in_sizes, int n_in,
                              void* d_out, int out_size, void* d_ws, size_t ws_size,
                              hipStream_t stream) {
    const float* S0  = (const float*)d_in[0];
    const float* I0  = (const float*)d_in[1];
    const float* nf  = (const float*)d_in[4];
    const void*  ei  = d_in[5];
    const float* ew  = (const float*)d_in[6];
    const float* Wm  = (const float*)d_in[7];
    const float* Wsf = (const float*)d_in[8];
    const float* bh  = (const float*)d_in[9];
    const float* wb  = (const float*)d_in[10];
    const float* bb  = (const float*)d_in[11];
    const float* wg  = (const float*)d_in[12];
    const float* bg  = (const float*)d_in[13];

    const int n = in_sizes[0];
    const int T = in_sizes[3];
    const int E = in_sizes[6];

    int colbits = 1;
    while ((1 << colbits) < n) ++colbits;           // n <= 2^colbits (17 @ 100K)
    float scale = (float)((1u << (32 - colbits)) - 1);
    float inv_scale = 1.0f / scale;
    const int scap2 = E / NSUB + E / (NSUB * 4) + 256;   // ~18 sigma headroom
    const int ovcap = E;                                  // always-correct spill

    char* ws = (char*)d_ws;
    size_t off = 0;
    auto alloc = [&](size_t bytes) {
        size_t p = off;
        off = (off + bytes + 255) & ~(size_t)255;
        return p;
    };
    float*  HC      = (float*)(ws + alloc((size_t)n * 64 * 4));
    __half* PMh     = (__half*)(ws + alloc((size_t)n * 64 * 2));
    __half* HCh     = (__half*)(ws + alloc((size_t)n * 64 * 2));
    float*  S       = (float*)(ws + alloc((size_t)n * 4));
    __half* Ih0     = (__half*)(ws + alloc((size_t)n * 2));
    __half* IhA     = (__half*)(ws + alloc((size_t)n * 2));
    __half* IhB     = (__half*)(ws + alloc((size_t)n * 2));
    int*    cnt     = (int*)(ws + alloc((size_t)n * 4));
    uint32_t* ev    = (uint32_t*)(ws + alloc((size_t)n * ELL_C * 4));
    int2*   staging = (int2*)(ws + alloc((size_t)NSUB * scap2 * 8));
    int2*   ovf     = (int2*)(ws + alloc((size_t)ovcap * 8));
    int*    gcur    = (int*)(ws + alloc((size_t)NSUB * 4));
    int*    ovcnt   = (int*)(ws + alloc(256));
    int*    flag    = (int*)(ws + alloc(256));
    if (off > ws_size) return;  // workspace too small: fail loudly (poisoned out)

    float* out       = (float*)d_out;
    float* beta_out  = out + (size_t)T * n;
    float* gamma_out = out + (size_t)T * n + n;

    hipMemcpyAsync(S, S0, (size_t)n * 4, hipMemcpyDeviceToDevice, stream);
    hipMemsetAsync(cnt, 0, (size_t)n * 4, stream);
    hipMemsetAsync(gcur, 0, (size_t)NSUB * 4, stream);
    hipMemsetAsync(ovcnt, 0, 256, stream);
    // NOTE: no ev memset -- all consumers read strictly < deg entries.

    // ELL build: 512-way bin -> per-sub-bin LDS row assembly -> overflow fixup.
    detect_i64<<<1, 256, 0, stream>>>((const long long*)ei, E, n, flag);
    k_bin512<<<NBIN, 256, 0, stream>>>(ei, ew, flag, E, n, colbits, scale,
                                       staging, scap2, gcur, ovf, ovcnt, ovcap);
    k_scatter512<<<NSUB, 256, 0, stream>>>(staging, scap2, gcur, n, cnt, ev);
    k_overflow<<<64, 256, 0, stream>>>(ovf, ovcnt, ovcap, cnt, ev);
    k_h16<<<(n + 255) / 256, 256, 0, stream>>>(I0, Ih0, n);

    // Loop-invariant precompute (MFMA projection).
    proj_mfma<<<(n + 63) / 64, 256, 0, stream>>>(nf, Wm, Wsf, bh, PMh, HC, n);
    edge_wide_ell<<<(n * 64 + 255) / 256, 256, 0, stream>>>(
        cnt, ev, PMh, HC, HCh, n, colbits, inv_scale);

    // 20-step scan: one fused kernel/step; fp32 I state lives in out rows,
    // fp16 gather mirror double-buffered.
    const uint32_t* HChu = (const uint32_t*)HCh;
    const float4* wmL4 = (const float4*)(Wm  + 64 * 64);
    const float4* wsL4 = (const float4*)(Wsf + 64 * 64);
    const float4* wb4  = (const float4*)wb;
    const float4* wg4  = (const float4*)wg;
    int swaves = (n + 3) / 4;
    int sblocks = (swaves * 64 + 255) / 256;
    for (int t = 0; t < T; ++t) {
        const float*  Iold = (t == 0) ? I0 : out + (size_t)(t - 1) * n;
        const __half* Ihp  = (t == 0) ? Ih0 : ((t & 1) ? IhA : IhB);
        __half*       Ihc  = (t & 1) ? IhB : IhA;
        step_fused4<<<sblocks, 256, 0, stream>>>(
            cnt, ev, HChu, wmL4, wsL4, wb4, bb, wg4, bg,
            Iold, Ihp, Ihc, S, out + (size_t)t * n, beta_out, gamma_out,
            n, t == T - 1 ? 1 : 0, colbits, inv_scale);
    }
}

// Round 23
// 428.894 us; speedup vs baseline: 1.2482x; 1.2482x over previous
//
#include <hip/hip_runtime.h>
#include <hip/hip_fp16.h>
#include <cstdint>
#include <cstddef>

#define DT_F 0.5f
#define ELL_C 64        // fixed ELL row capacity (Poisson(16): max deg ~45)
#define NSUB 512        // dst sub-bins (each ~n/512 nodes)
#define LCAP 14         // LDS bin depth in k_bin512
#define NBIN 1024       // k_bin512 blocks
#define NLOC_MAX 208    // max nodes per sub-bin for LDS row assembly

typedef _Float16 f16x8 __attribute__((ext_vector_type(8)));
typedef float f32x4 __attribute__((ext_vector_type(4)));

// ---------------------------------------------------------------------------
// edge_index dtype detection (reference says int64; harness doc says int).
__global__ void detect_i64(const long long* __restrict__ ei, int E, int n,
                           int* __restrict__ flag) {
    __shared__ int ok;
    if (threadIdx.x == 0) ok = 1;
    __syncthreads();
    int m = E < 2048 ? E : 2048;
    for (int i = threadIdx.x; i < m; i += blockDim.x) {
        long long v = ei[i];
        if (v < 0 || v >= (long long)n) ok = 0;  // benign race, all write 0
    }
    __syncthreads();
    if (threadIdx.x == 0) flag[0] = ok;
}

__device__ __forceinline__ int ld_idx(const void* ei, size_t pos, int w64) {
    return w64 ? (int)((const long long*)ei)[pos] : ((const int*)ei)[pos];
}

// ---------------------------------------------------------------------------
// Build pass 1 (validated R17): 512-way LDS binning, flush to staging.
__global__ void k_bin512(const void* __restrict__ ei, const float* __restrict__ ew,
                         const int* __restrict__ flag, int E, int n,
                         int colbits, float scale,
                         int2* __restrict__ staging, int scap2,
                         int* __restrict__ gcur,
                         int2* __restrict__ ovf, int* __restrict__ ovcnt, int ovcap) {
    __shared__ int2 bins[NSUB][LCAP];   // 57344 B
    __shared__ int bcnt[NSUB];
    __shared__ int gbase[NSUB];
    int tid = threadIdx.x;
    for (int b = tid; b < NSUB; b += 256) bcnt[b] = 0;
    __syncthreads();
    int per = (E + NBIN - 1) / NBIN;
    int e0 = blockIdx.x * per;
    int e1 = e0 + per; if (e1 > E) e1 = E;
    int w64 = flag[0];
    for (int e = e0 + tid; e < e1; e += 256) {
        int d = ld_idx(ei, (size_t)E + e, w64);
        uint32_t w15 = (uint32_t)(ew[e] * scale + 0.5f);
        uint32_t sw = (w15 << colbits) | (uint32_t)ld_idx(ei, e, w64);
        int sb = (int)(((long long)d * NSUB) / n);
        int p = atomicAdd(&bcnt[sb], 1);
        if (p < LCAP) {
            bins[sb][p] = make_int2(d, (int)sw);
        } else {
            int q = atomicAdd(ovcnt, 1);
            if (q < ovcap) ovf[q] = make_int2(d, (int)sw);
        }
    }
    __syncthreads();
    for (int b = tid; b < NSUB; b += 256) {
        int c = bcnt[b]; if (c > LCAP) c = LCAP;
        bcnt[b] = c;
        gbase[b] = atomicAdd(&gcur[b], c);
    }
    __syncthreads();
    for (int b = tid; b < NSUB; b += 256) {
        int c = bcnt[b], gb = gbase[b];
        for (int i = 0; i < c; ++i) {
            int pos = gb + i;
            if (pos < scap2) {
                staging[(size_t)b * scap2 + pos] = bins[b][i];
            } else {
                int q = atomicAdd(ovcnt, 1);
                if (q < ovcap) ovf[q] = bins[b][i];
            }
        }
    }
}

// Build pass 2 (validated R17): one block per sub-bin, LDS row assembly,
// coalesced single-write flush.
__global__ void k_scatter512(const int2* __restrict__ staging, int scap2,
                             const int* __restrict__ gcur, int n,
                             int* __restrict__ cnt, uint32_t* __restrict__ ev) {
    __shared__ uint32_t lrow[NLOC_MAX * 64];   // 53248 B
    __shared__ int lcnt[NLOC_MAX];
    int sb = blockIdx.x;
    int lo = (int)(((long long)sb * n + NSUB - 1) / NSUB);
    int hi = (int)(((long long)(sb + 1) * n + NSUB - 1) / NSUB);
    if (hi > n) hi = n;
    int nloc = hi - lo;
    int tid = threadIdx.x;
    int tot = gcur[sb]; if (tot > scap2) tot = scap2;
    if (nloc <= NLOC_MAX) {
        for (int i = tid; i < nloc; i += 256) lcnt[i] = 0;
        __syncthreads();
        for (int i = tid; i < tot; i += 256) {
            int2 t = staging[(size_t)sb * scap2 + i];
            int ni = t.x - lo;
            int p = atomicAdd(&lcnt[ni], 1);
            if (p < ELL_C) lrow[ni * 64 + p] = (uint32_t)t.y;
        }
        __syncthreads();
        for (int idx = tid; idx < nloc * 64; idx += 256) {
            int ni = idx >> 6, e = idx & 63;
            int c = lcnt[ni]; if (c > ELL_C) c = ELL_C;
            if (e < c) ev[(size_t)(lo + ni) * 64 + e] = lrow[idx];
        }
        for (int i = tid; i < nloc; i += 256) {
            int c = lcnt[i]; if (c > ELL_C) c = ELL_C;
            cnt[lo + i] = c;
        }
    } else {  // generic-n fallback: direct scatter (cnt pre-zeroed)
        for (int i = tid; i < tot; i += 256) {
            int2 t = staging[(size_t)sb * scap2 + i];
            int p = atomicAdd(&cnt[t.x], 1);
            if (p < ELL_C) ev[(size_t)t.x * 64 + p] = (uint32_t)t.y;
        }
    }
}

// Append rare overflow edges (normally 0) after row assembly.
__global__ void k_overflow(const int2* __restrict__ ovf, const int* __restrict__ ovcnt,
                           int ovcap, int* __restrict__ cnt, uint32_t* __restrict__ ev) {
    int tot = ovcnt[0]; if (tot > ovcap) tot = ovcap;
    for (int i = blockIdx.x * blockDim.x + threadIdx.x; i < tot;
         i += gridDim.x * blockDim.x) {
        int2 t = ovf[i];
        int p = atomicAdd(&cnt[t.x], 1);
        if (p < ELL_C) ev[(size_t)t.x * 64 + p] = (uint32_t)t.y;
    }
}

// ---------------------------------------------------------------------------
// I0 -> fp16 gather mirror.
__global__ void k_h16(const float* __restrict__ x, __half* __restrict__ y, int n) {
    int i = blockIdx.x * blockDim.x + threadIdx.x;
    if (i < n) y[i] = __float2half(x[i]);
}

// ---------------------------------------------------------------------------
// Projection via MATRIX CORES (validated R19: proj 72 -> <~15us, absmax ok).
__global__ void proj_mfma(const float* __restrict__ nf,
                          const float* __restrict__ Wm,   // (65,64) row-major
                          const float* __restrict__ Wsf,  // (65,64)
                          const float* __restrict__ bh,
                          __half* __restrict__ PMh, float* __restrict__ HC,
                          int n) {
    __shared__ _Float16 sW[2][8][512];   // [matrix][frag ks*4+jt][lane*8+el]
    int tid = threadIdx.x;
    for (int idx = tid; idx < 8192; idx += 256) {
        int m   = idx >> 12;
        int rem = idx & 4095;
        int f   = rem >> 9;
        int ln  = (rem >> 3) & 63;
        int el  = rem & 7;
        int ks = f >> 2, jt = f & 3;
        int k = ks * 32 + (ln >> 4) * 8 + el;
        int j = jt * 16 + (ln & 15);
        const float* W = m ? Wsf : Wm;
        sW[m][f][ln * 8 + el] = (_Float16)W[k * 64 + j];
    }
    __syncthreads();
    int w = tid >> 6, l = tid & 63;
    int kg = l >> 4;
    int node0 = blockIdx.x * 64 + w * 16;
    int nodeA = node0 + (l & 15);                  // A-fragment row
    f16x8 a0 = {}, a1 = {};
    if (nodeA < n) {
        const float* p = nf + (size_t)nodeA * 64 + kg * 8;
        float4 u0 = *(const float4*)(p);
        float4 u1 = *(const float4*)(p + 4);
        float4 v0 = *(const float4*)(p + 32);
        float4 v1 = *(const float4*)(p + 36);
        a0[0]=(_Float16)u0.x; a0[1]=(_Float16)u0.y; a0[2]=(_Float16)u0.z; a0[3]=(_Float16)u0.w;
        a0[4]=(_Float16)u1.x; a0[5]=(_Float16)u1.y; a0[6]=(_Float16)u1.z; a0[7]=(_Float16)u1.w;
        a1[0]=(_Float16)v0.x; a1[1]=(_Float16)v0.y; a1[2]=(_Float16)v0.z; a1[3]=(_Float16)v0.w;
        a1[4]=(_Float16)v1.x; a1[5]=(_Float16)v1.y; a1[6]=(_Float16)v1.z; a1[7]=(_Float16)v1.w;
    }
    f32x4 accm[4], accs[4];
#pragma unroll
    for (int jt = 0; jt < 4; ++jt) { accm[jt] = (f32x4){0.f,0.f,0.f,0.f};
                                     accs[jt] = (f32x4){0.f,0.f,0.f,0.f}; }
#pragma unroll
    for (int jt = 0; jt < 4; ++jt) {
        f16x8 bm0 = *(const f16x8*)&sW[0][jt][l * 8];
        f16x8 bm1 = *(const f16x8*)&sW[0][4 + jt][l * 8];
        accm[jt] = __builtin_amdgcn_mfma_f32_16x16x32_f16(a0, bm0, accm[jt], 0, 0, 0);
        accm[jt] = __builtin_amdgcn_mfma_f32_16x16x32_f16(a1, bm1, accm[jt], 0, 0, 0);
        f16x8 bs0 = *(const f16x8*)&sW[1][jt][l * 8];
        f16x8 bs1 = *(const f16x8*)&sW[1][4 + jt][l * 8];
        accs[jt] = __builtin_amdgcn_mfma_f32_16x16x32_f16(a0, bs0, accs[jt], 0, 0, 0);
        accs[jt] = __builtin_amdgcn_mfma_f32_16x16x32_f16(a1, bs1, accs[jt], 0, 0, 0);
    }
#pragma unroll
    for (int r = 0; r < 4; ++r) {
        int node = node0 + kg * 4 + r;              // D row
        if (node < n) {
#pragma unroll
            for (int jt = 0; jt < 4; ++jt) {
                int j = jt * 16 + (l & 15);         // D col
                PMh[(size_t)node * 64 + j] = __float2half(accm[jt][r]);
                HC[(size_t)node * 64 + j] = accs[jt][r] + bh[j];
            }
        }
    }
}

// Hoisted constant aggregation on ELL rows, fp16 PM gather, 8-edge unroll
// (8 independent 128B row-gathers in flight). Plain loads: ev/HC re-hit L2
// across the scan (R22 post-mortem: NT loads cost +105us total).
__global__ void edge_wide_ell(const int* __restrict__ cnt,
                              const uint32_t* __restrict__ ev,
                              const __half* __restrict__ PMh,
                              const float* __restrict__ HCin,
                              __half* __restrict__ HCh, int n,
                              int colbits, float inv_scale) {
    int wave = (blockIdx.x * blockDim.x + threadIdx.x) >> 6;
    int lane = threadIdx.x & 63;
    if (wave >= n) return;
    uint32_t cmask = (1u << colbits) - 1;
    int deg = cnt[wave]; if (deg > ELL_C) deg = ELL_C;
    int d8 = deg & ~7;
    int d4 = deg & ~3;
    const uint32_t* row = ev + (size_t)wave * ELL_C;
    float acc0 = 0.f, acc1 = 0.f, acc2 = 0.f, acc3 = 0.f;
    for (int e = 0; e < d8; e += 8) {
        uint4 qa = *(const uint4*)&row[e];
        uint4 qb = *(const uint4*)&row[e + 4];
        float v0 = __half2float(PMh[(size_t)(qa.x & cmask) * 64 + lane]);
        float v1 = __half2float(PMh[(size_t)(qa.y & cmask) * 64 + lane]);
        float v2 = __half2float(PMh[(size_t)(qa.z & cmask) * 64 + lane]);
        float v3 = __half2float(PMh[(size_t)(qa.w & cmask) * 64 + lane]);
        float v4 = __half2float(PMh[(size_t)(qb.x & cmask) * 64 + lane]);
        float v5 = __half2float(PMh[(size_t)(qb.y & cmask) * 64 + lane]);
        float v6 = __half2float(PMh[(size_t)(qb.z & cmask) * 64 + lane]);
        float v7 = __half2float(PMh[(size_t)(qb.w & cmask) * 64 + lane]);
        acc0 = fmaf((float)(qa.x >> colbits) * inv_scale, v0, acc0);
        acc1 = fmaf((float)(qa.y >> colbits) * inv_scale, v1, acc1);
        acc2 = fmaf((float)(qa.z >> colbits) * inv_scale, v2, acc2);
        acc3 = fmaf((float)(qa.w >> colbits) * inv_scale, v3, acc3);
        acc0 = fmaf((float)(qb.x >> colbits) * inv_scale, v4, acc0);
        acc1 = fmaf((float)(qb.y >> colbits) * inv_scale, v5, acc1);
        acc2 = fmaf((float)(qb.z >> colbits) * inv_scale, v6, acc2);
        acc3 = fmaf((float)(qb.w >> colbits) * inv_scale, v7, acc3);
    }
    if (d8 < d4) {
        uint4 q = *(const uint4*)&row[d8];
        float v0 = __half2float(PMh[(size_t)(q.x & cmask) * 64 + lane]);
        float v1 = __half2float(PMh[(size_t)(q.y & cmask) * 64 + lane]);
        float v2 = __half2float(PMh[(size_t)(q.z & cmask) * 64 + lane]);
        float v3 = __half2float(PMh[(size_t)(q.w & cmask) * 64 + lane]);
        acc0 = fmaf((float)(q.x >> colbits) * inv_scale, v0, acc0);
        acc1 = fmaf((float)(q.y >> colbits) * inv_scale, v1, acc1);
        acc2 = fmaf((float)(q.z >> colbits) * inv_scale, v2, acc2);
        acc3 = fmaf((float)(q.w >> colbits) * inv_scale, v3, acc3);
    }
    for (int e = d4; e < deg; ++e) {                 // scalar tail (<=3)
        uint32_t q = row[e];
        acc0 = fmaf((float)(q >> colbits) * inv_scale,
                    __half2float(PMh[(size_t)(q & cmask) * 64 + lane]), acc0);
    }
    size_t o = (size_t)wave * 64 + lane;
    HCh[o] = __float2half(HCin[o] + ((acc0 + acc1) + (acc2 + acc3)));
}

// ---------------------------------------------------------------------------
// Fused per-step kernel, 4 nodes/wave, 16 lanes/node, ELL rows.
// fp16 I-gather mirror; fp32 state in out rows. Plain loads: ev (6.4MB) +
// HCh (12.8MB) stay L2-resident ACROSS steps (32MB aggregate L2).
__global__ void step_fused4(const int* __restrict__ cnt,
                            const uint32_t* __restrict__ ev,
                            const __half2* __restrict__ HCh2,
                            const float4* __restrict__ wmL4,  // W_msg row 64
                            const float4* __restrict__ wsL4,  // W_self row 64
                            const float4* __restrict__ wb4, const float* __restrict__ bb,
                            const float4* __restrict__ wg4, const float* __restrict__ bg,
                            const float* __restrict__ I_old,   // fp32 (out row)
                            const __half* __restrict__ Ih_old, // fp16 mirror
                            __half* __restrict__ Ih_new,
                            float* __restrict__ S,
                            float* __restrict__ Iseq_t,      // = I_new (fp32)
                            float* __restrict__ beta_out, float* __restrict__ gamma_out,
                            int n, int last, int colbits, float inv_scale) {
    int wid  = (blockIdx.x * blockDim.x + threadIdx.x) >> 6;
    int lane = threadIdx.x & 63;
    int l16  = lane & 15;
    int node = wid * 4 + (lane >> 4);
    if (node >= n) return;
    uint32_t cmask = (1u << colbits) - 1;
    int deg = cnt[node]; if (deg > ELL_C) deg = ELL_C;
    const uint32_t* row = ev + (size_t)node * ELL_C;
    float f = 0.f;
    for (int e = l16; e < deg; e += 16) {
        uint32_t p = row[e];
        f = fmaf((float)(p >> colbits) * inv_scale,
                 __half2float(Ih_old[p & cmask]), f);
    }
    f += __shfl_xor(f, 1); f += __shfl_xor(f, 2);
    f += __shfl_xor(f, 4); f += __shfl_xor(f, 8);   // force, all 16 lanes
    float Iv = I_old[node];
    __half2 hA = HCh2[(size_t)node * 32 + l16 * 2];
    __half2 hB = HCh2[(size_t)node * 32 + l16 * 2 + 1];
    float2 fA = __half22float2(hA);
    float2 fB = __half22float2(hB);
    float4 wm = wmL4[l16], wsv = wsL4[l16];
    float4 h;
    h.x = fmaxf(fmaf(f, wm.x, fmaf(Iv, wsv.x, fA.x)), 0.f);
    h.y = fmaxf(fmaf(f, wm.y, fmaf(Iv, wsv.y, fA.y)), 0.f);
    h.z = fmaxf(fmaf(f, wm.z, fmaf(Iv, wsv.z, fB.x)), 0.f);
    h.w = fmaxf(fmaf(f, wm.w, fmaf(Iv, wsv.w, fB.y)), 0.f);
    float4 wbv = wb4[l16], wgv = wg4[l16];
    float pb = fmaf(h.x, wbv.x, fmaf(h.y, wbv.y, fmaf(h.z, wbv.z, h.w * wbv.w)));
    float pg = fmaf(h.x, wgv.x, fmaf(h.y, wgv.y, fmaf(h.z, wgv.z, h.w * wgv.w)));
    pb += __shfl_xor(pb, 1); pg += __shfl_xor(pg, 1);
    pb += __shfl_xor(pb, 2); pg += __shfl_xor(pg, 2);
    pb += __shfl_xor(pb, 4); pg += __shfl_xor(pg, 4);
    pb += __shfl_xor(pb, 8); pg += __shfl_xor(pg, 8);
    if (l16 == 0) {
        float beta  = 1.f / (1.f + expf(-(pb + bb[0])));
        float gamma = 1.f / (1.f + expf(-(pg + bg[0])));
        float fc = fminf(fmaxf(f, 0.f), 1000.f);
        float Sv = S[node];
        float inf_ = beta * Sv * fc;
        float rec  = gamma * Iv;
        float Sn = fminf(fmaxf(Sv - inf_ * DT_F, 0.f), 1.f);
        float In = fminf(fmaxf(Iv + (inf_ - rec) * DT_F, 0.f), 1.f);
        S[node] = Sn;
        Iseq_t[node] = In;                 // exact fp32 state + output
        Ih_new[node] = __float2half(In);   // gather mirror for step t+1
        if (last) { beta_out[node] = beta; gamma_out[node] = gamma; }
    }
}

// ---------------------------------------------------------------------------
extern "C" void kernel_launch(void* const* d_in, const int* in_sizes, int n_in,
                              void* d_out, int out_size, void* d_ws, size_t ws_size,
                              hipStream_t stream) {
    const float* S0  = (const float*)d_in[0];
    const float* I0  = (const float*)d_in[1];
    const float* nf  = (const float*)d_in[4];
    const void*  ei  = d_in[5];
    const float* ew  = (const float*)d_in[6];
    const float* Wm  = (const float*)d_in[7];
    const float* Wsf = (const float*)d_in[8];
    const float* bh  = (const float*)d_in[9];
    const float* wb  = (const float*)d_in[10];
    const float* bb  = (const float*)d_in[11];
    const float* wg  = (const float*)d_in[12];
    const float* bg  = (const float*)d_in[13];

    const int n = in_sizes[0];
    const int T = in_sizes[3];
    const int E = in_sizes[6];

    int colbits = 1;
    while ((1 << colbits) < n) ++colbits;           // n <= 2^colbits (17 @ 100K)
    float scale = (float)((1u << (32 - colbits)) - 1);
    float inv_scale = 1.0f / scale;
    const int scap2 = E / NSUB + E / (NSUB * 4) + 256;   // ~18 sigma headroom
    const int ovcap = E;                                  // always-correct spill

    char* ws = (char*)d_ws;
    size_t off = 0;
    auto alloc = [&](size_t bytes) {
        size_t p = off;
        off = (off + bytes + 255) & ~(size_t)255;
        return p;
    };
    float*  HC      = (float*)(ws + alloc((size_t)n * 64 * 4));
    __half* PMh     = (__half*)(ws + alloc((size_t)n * 64 * 2));
    __half* HCh     = (__half*)(ws + alloc((size_t)n * 64 * 2));
    float*  S       = (float*)(ws + alloc((size_t)n * 4));
    __half* Ih0     = (__half*)(ws + alloc((size_t)n * 2));
    __half* IhA     = (__half*)(ws + alloc((size_t)n * 2));
    __half* IhB     = (__half*)(ws + alloc((size_t)n * 2));
    int*    cnt     = (int*)(ws + alloc((size_t)n * 4));
    uint32_t* ev    = (uint32_t*)(ws + alloc((size_t)n * ELL_C * 4));
    int2*   staging = (int2*)(ws + alloc((size_t)NSUB * scap2 * 8));
    int2*   ovf     = (int2*)(ws + alloc((size_t)ovcap * 8));
    int*    gcur    = (int*)(ws + alloc((size_t)NSUB * 4));
    int*    ovcnt   = (int*)(ws + alloc(256));
    int*    flag    = (int*)(ws + alloc(256));
    if (off > ws_size) return;  // workspace too small: fail loudly (poisoned out)

    float* out       = (float*)d_out;
    float* beta_out  = out + (size_t)T * n;
    float* gamma_out = out + (size_t)T * n + n;

    hipMemcpyAsync(S, S0, (size_t)n * 4, hipMemcpyDeviceToDevice, stream);
    hipMemsetAsync(cnt, 0, (size_t)n * 4, stream);
    hipMemsetAsync(gcur, 0, (size_t)NSUB * 4, stream);
    hipMemsetAsync(ovcnt, 0, 256, stream);
    // NOTE: no ev memset -- all consumers read strictly < deg entries.

    // ELL build: 512-way bin -> per-sub-bin LDS row assembly -> overflow fixup.
    detect_i64<<<1, 256, 0, stream>>>((const long long*)ei, E, n, flag);
    k_bin512<<<NBIN, 256, 0, stream>>>(ei, ew, flag, E, n, colbits, scale,
                                       staging, scap2, gcur, ovf, ovcnt, ovcap);
    k_scatter512<<<NSUB, 256, 0, stream>>>(staging, scap2, gcur, n, cnt, ev);
    k_overflow<<<64, 256, 0, stream>>>(ovf, ovcnt, ovcap, cnt, ev);
    k_h16<<<(n + 255) / 256, 256, 0, stream>>>(I0, Ih0, n);

    // Loop-invariant precompute (MFMA projection).
    proj_mfma<<<(n + 63) / 64, 256, 0, stream>>>(nf, Wm, Wsf, bh, PMh, HC, n);
    edge_wide_ell<<<(n * 64 + 255) / 256, 256, 0, stream>>>(
        cnt, ev, PMh, HC, HCh, n, colbits, inv_scale);

    // 20-step scan: one fused kernel/step; fp32 I state lives in out rows,
    // fp16 gather mirror double-buffered.
    const __half2* HCh2 = (const __half2*)HCh;
    const float4* wmL4 = (const float4*)(Wm  + 64 * 64);
    const float4* wsL4 = (const float4*)(Wsf + 64 * 64);
    const float4* wb4  = (const float4*)wb;
    const float4* wg4  = (const float4*)wg;
    int swaves = (n + 3) / 4;
    int sblocks = (swaves * 64 + 255) / 256;
    for (int t = 0; t < T; ++t) {
        const float*  Iold = (t == 0) ? I0 : out + (size_t)(t - 1) * n;
        const __half* Ihp  = (t == 0) ? Ih0 : ((t & 1) ? IhA : IhB);
        __half*       Ihc  = (t & 1) ? IhB : IhA;
        step_fused4<<<sblocks, 256, 0, stream>>>(
            cnt, ev, HCh2, wmL4, wsL4, wb4, bb, wg4, bg,
            Iold, Ihp, Ihc, S, out + (size_t)t * n, beta_out, gamma_out,
            n, t == T - 1 ? 1 : 0, colbits, inv_scale);
    }
}